// Round 13
// baseline (3731.254 us; speedup 1.0000x reference)
//
#include <hip/hip_runtime.h>
#include <stdint.h>

typedef unsigned short u16;
typedef unsigned int   u32;
typedef _Float16 f16x8 __attribute__((ext_vector_type(8)));
typedef __attribute__((ext_vector_type(16))) float f16v;
typedef __attribute__((ext_vector_type(2)))  float f2v;

#define JJ 17
#define CC 128
#define BB 14
#define ROWS (BB*JJ)     // 238
#define PP 256
#define XP 136           // u16 pitch: 272B rows -> every frag 16B-aligned (b128)
#define H1P 130          // f32 pitch for h1 (aliases X planes)
#define NLAYERS 5
#define NT 512

#define XBUF_BYTES (2*PP*XP*2)           // 139264: xh+xl; h1 f32[256][130]=133120 alias
#define ADJS_OFF   XBUF_BYTES            // 139264
#define DIAG_OFF   (ADJS_OFF + 1216)     // 140480
#define BIAS_OFF   (DIAG_OFF + 1024)     // 141504
#define LDS_BYTES  (BIAS_OFF + 512)      // 142016 -> 1 block/CU

#define MFMA __builtin_amdgcn_mfma_f32_32x32x16_f16

__device__ __forceinline__ u16 h2b(_Float16 h) {
  union { _Float16 h; u16 b; } c; c.h = h; return c.b;
}
__device__ __forceinline__ _Float16 b2h(u16 b) {
  union { u16 b; _Float16 h; } c; c.b = b; return c.h;
}
__device__ __forceinline__ float wred(float v) {
  #pragma unroll
  for (int m = 32; m >= 1; m >>= 1) v += __shfl_xor(v, m, 64);
  return v;
}
__device__ __forceinline__ f16x8 u4f8(uint4 v) {
  union { uint4 u; f16x8 f; } c; c.u = v; return c.f;
}

// ---- setup: W -> f16 in wave-coalesced frag layout ws[w][kh][kgl][col][8] ----
__global__ void __launch_bounds__(256)
wprep(const float* __restrict__ W0, const float* __restrict__ W1,
      u16* __restrict__ wsH)
{
  __shared__ float wt[64*130];
  const int w01 = blockIdx.x;
  const float* Wp = w01 ? W1 : W0;
  const int tid = threadIdx.x;
  for (int kh = 0; kh < 2; ++kh) {
    if (kh) __syncthreads();
    #pragma unroll
    for (int i = 0; i < 32; ++i) {
      int idx = tid + i*256;           // [64 kk][128 col] coalesced read
      int kk = idx >> 7, col = idx & 127;
      wt[kk*130 + col] = Wp[(kh*64 + kk)*128 + col];
    }
    __syncthreads();
    #pragma unroll
    for (int i = 0; i < 32; ++i) {
      int idx = tid + i*256;           // 0..8191
      int e = idx & 7, col = (idx >> 3) & 127, kgl = idx >> 10;   // kgl 0..7
      int kk = kgl*8 + e;              // local k within this 64-half
      wsH[(size_t)w01*16384 + kh*8192 + idx] = h2b((_Float16)wt[kk*130 + col]);
    }
  }
}

__global__ void __launch_bounds__(NT, 2)
gconv_fused(const float* __restrict__ x, const float* __restrict__ x0,
            const float* __restrict__ adj, const u16* __restrict__ wsH,
            const float* __restrict__ bvec, const float* __restrict__ gamma,
            const float* __restrict__ beta, float* __restrict__ out, int totRows)
{
  extern __shared__ char smem[];
  u16*   xh    = (u16*)smem;                   // [PP][XP] x hi (f16)
  u16*   xl    = xh + PP*XP;                   // x lo (f16)
  float* h1    = (float*)smem;                 // alias, [PP][H1P] f32
  float* adjs  = (float*)(smem + ADJS_OFF);    // [289] 0.8*adj, diag zeroed
  float* diag8 = (float*)(smem + DIAG_OFF);    // [256]
  float* biasl = (float*)(smem + BIAS_OFF);    // [128]

  const int tid  = threadIdx.x;
  const int lane = tid & 63;
  const int wid  = tid >> 6;        // 0..7
  const int wm   = wid >> 2;        // 0..1  (M half: 128 rows each)
  const int wn   = wid & 3;         // 0..3  (N tile)
  const int g    = lane >> 5;
  const int nl   = lane & 31;
  const int ccol = wn*32 + nl;
  const int grow0 = blockIdx.x * ROWS;

  // ---- W (f16) to regs from coalesced ws layout: 1KB/instr, L2-hot
  f16x8 whi[2][8];
  #pragma unroll
  for (int w01 = 0; w01 < 2; ++w01) {
    const u16* bh = wsH + (size_t)w01*16384 + g*1024 + ccol*8;
    #pragma unroll
    for (int ks = 0; ks < 8; ++ks)
      whi[w01][ks] = u4f8(*(const uint4*)&bh[ks*2048]);
  }

  // ---- x -> xh/xl f16 planes (float4 in); pad rows zero
  #pragma unroll
  for (int i = 0; i < 16; ++i) {
    int el4 = tid + i*NT;              // 8192 float4 = 256 rows x 128
    int r = el4 >> 5, c4 = (el4 & 31) << 2;
    float4 v = make_float4(0.f, 0.f, 0.f, 0.f);
    if (r < ROWS && (grow0 + r) < totRows)
      v = *(const float4*)&x[(size_t)(grow0 + r)*CC + c4];
    u16 sh[4], sl[4];
    float vv[4] = {v.x, v.y, v.z, v.w};
    #pragma unroll
    for (int e = 0; e < 4; ++e) {
      _Float16 hh = (_Float16)vv[e];
      sh[e] = h2b(hh);
      sl[e] = h2b((_Float16)(vv[e] - (float)hh));
    }
    *(uint2*)&xh[r*XP + c4] = make_uint2((u32)sh[0] | ((u32)sh[1]<<16), (u32)sh[2] | ((u32)sh[3]<<16));
    *(uint2*)&xl[r*XP + c4] = make_uint2((u32)sl[0] | ((u32)sl[1]<<16), (u32)sl[2] | ((u32)sl[3]<<16));
  }
  if (tid < JJ*JJ) {
    int j = tid / JJ, k = tid - j*JJ;
    adjs[tid] = (j == k) ? 0.f : 0.8f * adj[tid];
  }
  if (tid >= 300 && tid < 300 + 128) biasl[tid - 300] = bvec[tid - 300];
  if (tid < 256) {
    int j = tid % JJ;
    diag8[tid] = (tid < ROWS) ? 0.8f * adj[j*JJ + j] : 0.f;
  }
  __syncthreads();

  // ================= layer loop (LDS/L2 only) =================
  #pragma unroll 1
  for (int layer = 0; layer < NLAYERS; ++layer) {
    f16v acc0[4], acc1[4];
    #pragma unroll
    for (int mt = 0; mt < 4; ++mt)
      #pragma unroll
      for (int i = 0; i < 16; ++i) { acc0[mt][i] = 0.f; acc1[mt][i] = 0.f; }

    // ---- GEMM: per ks: 8x ds_read_b128 + 16 MFMA (latency self-covered)
    #pragma unroll
    for (int ks = 0; ks < 8; ++ks) {
      #pragma unroll
      for (int mt = 0; mt < 4; ++mt) {
        const int xb = (wm*128 + mt*32 + nl)*XP + ks*16 + 8*g;
        f16x8 ah = *(const f16x8*)&xh[xb];
        f16x8 al = *(const f16x8*)&xl[xb];
        acc0[mt] = MFMA(ah, whi[0][ks], acc0[mt], 0, 0, 0);
        acc0[mt] = MFMA(al, whi[0][ks], acc0[mt], 0, 0, 0);
        acc1[mt] = MFMA(ah, whi[1][ks], acc1[mt], 0, 0, 0);
        acc1[mt] = MFMA(al, whi[1][ks], acc1[mt], 0, 0, 0);
      }
      __builtin_amdgcn_sched_barrier(0);   // cap fragment liveness per K-step
    }
    __syncthreads();   // (1) xh/xl reads done (h1 aliases them)

    // ---- epilogue: acc1 (X@W1) -> h1
    #pragma unroll
    for (int mt = 0; mt < 4; ++mt)
      #pragma unroll
      for (int q = 0; q < 16; ++q) {
        int row = wm*128 + mt*32 + (q&3) + 8*(q>>2) + 4*g;
        h1[row*H1P + ccol] = acc1[mt][q];
      }
    __syncthreads();   // (2) h1 complete

    // ---- joint mix in place: waves 0-5 take 2 elems, 6-7 take 1
    #pragma unroll 1
    for (int pass = 0; pass < 2; ++pass) {
      int e = wid + pass*8;
      if (e < BB) {                    // wave-uniform
        const int rb = e * JJ;
        f2v h[JJ];
        #pragma unroll
        for (int k = 0; k < JJ; ++k)
          h[k] = *(const f2v*)&h1[(rb+k)*H1P + 2*lane];
        #pragma unroll 2
        for (int j = 0; j < JJ; ++j) {
          f2v m; m.x = 0.f; m.y = 0.f;
          #pragma unroll
          for (int k = 0; k < JJ; ++k) {
            float a = adjs[j*JJ + k];
            m.x += a * h[k].x; m.y += a * h[k].y;
          }
          *(f2v*)&h1[(rb+j)*H1P + 2*lane] = m;
        }
      }
    }
    __syncthreads();   // (3) mix complete

    // ---- combine A: acc0 <- 0.2*x0 + diag*acc0 + h1_mix + b  (h1 reads -> regs)
    #pragma unroll
    for (int mt = 0; mt < 4; ++mt)
      #pragma unroll
      for (int q = 0; q < 16; ++q) {
        int row = wm*128 + mt*32 + (q&3) + 8*(q>>2) + 4*g;
        int grow = grow0 + row;
        float x0v = (row < ROWS && grow < totRows) ? x0[(size_t)grow*CC + ccol] : 0.f;
        acc0[mt][q] = 0.2f*x0v + diag8[row]*acc0[mt][q] + h1[row*H1P + ccol] + biasl[ccol];
      }
    __syncthreads();   // (4) ALL h1 reads drained before alias overwrite

    // ---- combine B: split acc0 (regs) -> xh/xl planes; no h1 access
    #pragma unroll
    for (int mt = 0; mt < 4; ++mt)
      #pragma unroll
      for (int q = 0; q < 16; ++q) {
        int row = wm*128 + mt*32 + (q&3) + 8*(q>>2) + 4*g;
        float v = acc0[mt][q];
        _Float16 hh = (_Float16)v;
        xh[row*XP + ccol] = h2b(hh);
        xl[row*XP + ccol] = h2b((_Float16)(v - (float)hh));
      }
    __syncthreads();   // (5) X planes ready
  }

  // ---- LayerNorm + store
  float ga = gamma[lane], g2 = gamma[64+lane];
  float ba = beta[lane],  b2f = beta[64+lane];
  #pragma unroll 1
  for (int i = 0; i < 30; ++i) {
    int r = wid + 8*i;               // wave-uniform, covers 0..239
    if (r >= ROWS) continue;
    int grow = grow0 + r;
    if (grow >= totRows) continue;
    int xb = r*XP;
    float xa = (float)b2h(xh[xb+lane])    + (float)b2h(xl[xb+lane]);
    float xc = (float)b2h(xh[xb+64+lane]) + (float)b2h(xl[xb+64+lane]);
    float mu = wred(xa + xc) * (1.f/128.f);
    float da = xa - mu, dc = xc - mu;
    float vs = wred(da*da + dc*dc) * (1.f/128.f);
    float rs = rsqrtf(vs + 1e-10f);
    size_t ob = (size_t)grow*CC;
    out[ob + lane]      = da*rs*ga + ba;
    out[ob + 64 + lane] = dc*rs*g2 + b2f;
  }
}

extern "C" void kernel_launch(void* const* d_in, const int* in_sizes, int n_in,
                              void* d_out, int out_size, void* d_ws, size_t ws_size,
                              hipStream_t stream) {
  const float* x   = (const float*)d_in[0];
  const float* x0  = (const float*)d_in[1];
  const float* adj = (const float*)d_in[2];
  const float* W0  = (const float*)d_in[3];
  const float* W1  = (const float*)d_in[4];
  const float* bv  = (const float*)d_in[5];
  const float* ga  = (const float*)d_in[6];
  const float* be  = (const float*)d_in[7];
  u16* wsH = (u16*)d_ws;                    // [2][2][8][128][8] f16
  int totRows = in_sizes[0] / CC;
  int nBatch  = totRows / JJ;
  int grid    = (nBatch + BB - 1) / BB;
  wprep<<<dim3(2), dim3(256), 0, stream>>>(W0, W1, wsH);
  hipFuncSetAttribute((const void*)gconv_fused,
                      hipFuncAttributeMaxDynamicSharedMemorySize, LDS_BYTES);
  gconv_fused<<<dim3(grid), dim3(NT), LDS_BYTES, stream>>>(
      x, x0, adj, wsH, bv, ga, be, (float*)d_out, totRows);
}

// Round 14
// 708.129 us; speedup vs baseline: 5.2692x; 5.2692x over previous
//
#include <hip/hip_runtime.h>
#include <stdint.h>

typedef unsigned short u16;
typedef unsigned int   u32;
typedef _Float16 f16x8 __attribute__((ext_vector_type(8)));
typedef __attribute__((ext_vector_type(16))) float f16v;
typedef __attribute__((ext_vector_type(2)))  float f2v;

#define JJ 17
#define CC 128
#define BB 7
#define ROWS (BB*JJ)     // 119
#define PP 128
#define XP 136           // u16 pitch: 272B rows -> every frag 16B-aligned (b128)
#define H1P 130          // f32 pitch for h1 (separate buffer, no alias)
#define NLAYERS 5
#define NT 512

#define XBUF_BYTES (2*PP*XP*2)            // 69632: xh + xl u16 planes
#define H1_OFF     XBUF_BYTES             // 69632
#define ADJS_OFF   (H1_OFF + PP*H1P*4)    // 69632+66560 = 136192
#define DIAG_OFF   (ADJS_OFF + 1216)      // 137408
#define BIAS_OFF   (DIAG_OFF + 512)       // 137920
#define LDS_BYTES  (BIAS_OFF + 512)       // 138432 -> 1 block/CU

#define MFMA __builtin_amdgcn_mfma_f32_32x32x16_f16

__device__ __forceinline__ u16 h2b(_Float16 h) {
  union { _Float16 h; u16 b; } c; c.h = h; return c.b;
}
__device__ __forceinline__ _Float16 b2h(u16 b) {
  union { u16 b; _Float16 h; } c; c.b = b; return c.h;
}
__device__ __forceinline__ float wred(float v) {
  #pragma unroll
  for (int m = 32; m >= 1; m >>= 1) v += __shfl_xor(v, m, 64);
  return v;
}
__device__ __forceinline__ f16x8 u4f8(uint4 v) {
  union { uint4 u; f16x8 f; } c; c.u = v; return c.f;
}

// ---- setup: W0/W1 -> f16, frag layout ws[w][col][k] ----
__global__ void __launch_bounds__(256)
wprep(const float* __restrict__ W0, const float* __restrict__ W1,
      u16* __restrict__ wsH)
{
  __shared__ float wt[64*130];
  const int w01 = blockIdx.x;
  const float* Wp = w01 ? W1 : W0;
  const int tid = threadIdx.x;
  for (int kh = 0; kh < 2; ++kh) {
    if (kh) __syncthreads();
    #pragma unroll
    for (int i = 0; i < 32; ++i) {
      int idx = tid + i*256;           // [64 kk][128 col] coalesced read
      int kk = idx >> 7, col = idx & 127;
      wt[kk*130 + col] = Wp[(kh*64 + kk)*128 + col];
    }
    __syncthreads();
    #pragma unroll
    for (int i = 0; i < 32; ++i) {
      int idx = tid + i*256;           // [128 col][64 kk] coalesced write
      int col = idx >> 6, kk = idx & 63;
      wsH[(size_t)(w01*128 + col)*128 + kh*64 + kk] = h2b((_Float16)wt[kk*130 + col]);
    }
  }
}

__global__ void __launch_bounds__(NT, 2)
gconv_fused(const float* __restrict__ x, const float* __restrict__ x0,
            const float* __restrict__ adj, const u16* __restrict__ wsH,
            const float* __restrict__ bvec, const float* __restrict__ gamma,
            const float* __restrict__ beta, float* __restrict__ out, int totRows)
{
  extern __shared__ char smem[];
  u16*   xh    = (u16*)smem;                   // [PP][XP] x hi (f16)
  u16*   xl    = xh + PP*XP;                   // x lo (f16)
  float* h1    = (float*)(smem + H1_OFF);      // [PP][H1P] f32 — separate, no alias
  float* adjs  = (float*)(smem + ADJS_OFF);    // [289] 0.8*adj, diag zeroed
  float* diag8 = (float*)(smem + DIAG_OFF);    // [128]
  float* biasl = (float*)(smem + BIAS_OFF);    // [128]

  const int tid  = threadIdx.x;
  const int lane = tid & 63;
  const int wid  = tid >> 6;        // 0..7
  const int wm   = wid >> 2;        // 0..1  (M half)
  const int wn   = wid & 3;         // 0..3  (N tile)
  const int g    = lane >> 5;
  const int nl   = lane & 31;
  const int ccol = wn*32 + nl;
  const int grow0 = blockIdx.x * ROWS;

  // ---- W (f16) straight to regs from precomputed ws (L2-hot): 64 VGPRs
  f16x8 whi[2][8];
  #pragma unroll
  for (int w01 = 0; w01 < 2; ++w01) {
    const u16* bh = wsH + (size_t)(w01*128 + ccol)*128;
    #pragma unroll
    for (int ks = 0; ks < 8; ++ks)
      whi[w01][ks] = u4f8(*(const uint4*)&bh[ks*16 + 8*g]);
  }

  // ---- x0 -> 16 packed-f16 regs (accumulator layout), read once
  u32 x0p[2][8];
  #pragma unroll
  for (int mt = 0; mt < 2; ++mt)
    #pragma unroll
    for (int qp = 0; qp < 8; ++qp) {
      u32 pk = 0;
      #pragma unroll
      for (int h = 0; h < 2; ++h) {
        int q = qp*2 + h;
        int row = wm*64 + mt*32 + (q&3) + 8*(q>>2) + 4*g;
        int grow = grow0 + row;
        u16 bits = 0;
        if (row < ROWS && grow < totRows)
          bits = h2b((_Float16)x0[(size_t)grow*CC + ccol]);
        pk |= ((u32)bits) << (16*h);
      }
      x0p[mt][qp] = pk;
    }

  // ---- x -> xh/xl f16 planes (float4 in); pad rows zero
  #pragma unroll
  for (int i = 0; i < 8; ++i) {
    int el4 = tid + i*NT;              // 4096 float4 = 128 rows x 128
    int r = el4 >> 5, c4 = (el4 & 31) << 2;
    float4 v = make_float4(0.f, 0.f, 0.f, 0.f);
    if (r < ROWS && (grow0 + r) < totRows)
      v = *(const float4*)&x[(size_t)(grow0 + r)*CC + c4];
    u16 sh[4], sl[4];
    float vv[4] = {v.x, v.y, v.z, v.w};
    #pragma unroll
    for (int e = 0; e < 4; ++e) {
      _Float16 hh = (_Float16)vv[e];
      sh[e] = h2b(hh);
      sl[e] = h2b((_Float16)(vv[e] - (float)hh));
    }
    *(uint2*)&xh[r*XP + c4] = make_uint2((u32)sh[0] | ((u32)sh[1]<<16), (u32)sh[2] | ((u32)sh[3]<<16));
    *(uint2*)&xl[r*XP + c4] = make_uint2((u32)sl[0] | ((u32)sl[1]<<16), (u32)sl[2] | ((u32)sl[3]<<16));
  }
  if (tid < JJ*JJ) {
    int j = tid / JJ, k = tid - j*JJ;
    adjs[tid] = (j == k) ? 0.f : 0.8f * adj[tid];
  }
  if (tid < PP) {
    int j = tid % JJ;
    diag8[tid] = (tid < ROWS) ? 0.8f * adj[j*JJ + j] : 0.f;
  }
  if (tid >= 128 && tid < 256) biasl[tid - 128] = bvec[tid - 128];
  __syncthreads();

  // ================= layer loop (3 barriers; no global traffic) =================
  #pragma unroll 1
  for (int layer = 0; layer < NLAYERS; ++layer) {
    f16v acc0[2], acc1[2];
    #pragma unroll
    for (int mt = 0; mt < 2; ++mt)
      #pragma unroll
      for (int i = 0; i < 16; ++i) { acc0[mt][i] = 0.f; acc1[mt][i] = 0.f; }

    // ---- GEMM: per ks per mt: 2x ds_read_b128 + 4 MFMA
    #pragma unroll
    for (int ks = 0; ks < 8; ++ks) {
      #pragma unroll
      for (int mt = 0; mt < 2; ++mt) {
        const int xb = (wm*64 + mt*32 + nl)*XP + ks*16 + 8*g;
        f16x8 ah = *(const f16x8*)&xh[xb];
        f16x8 al = *(const f16x8*)&xl[xb];
        acc0[mt] = MFMA(ah, whi[0][ks], acc0[mt], 0, 0, 0);
        acc0[mt] = MFMA(al, whi[0][ks], acc0[mt], 0, 0, 0);
        acc1[mt] = MFMA(ah, whi[1][ks], acc1[mt], 0, 0, 0);
        acc1[mt] = MFMA(al, whi[1][ks], acc1[mt], 0, 0, 0);
      }
      __builtin_amdgcn_sched_barrier(0);   // cap fragment liveness per K-step
    }

    // ---- epilogue: acc1 (X@W1) -> h1 (separate buffer: no barrier needed first)
    #pragma unroll
    for (int mt = 0; mt < 2; ++mt)
      #pragma unroll
      for (int q = 0; q < 16; ++q) {
        int row = wm*64 + mt*32 + (q&3) + 8*(q>>2) + 4*g;
        h1[row*H1P + ccol] = acc1[mt][q];
      }
    __syncthreads();   // (1) h1 complete

    // ---- joint mix in place (wave wid = batch elem; wave 7 idles)
    if (wid < BB) {
      const int rb = wid * JJ;
      f2v h[JJ];
      #pragma unroll
      for (int k = 0; k < JJ; ++k)
        h[k] = *(const f2v*)&h1[(rb+k)*H1P + 2*lane];
      #pragma unroll 2
      for (int j = 0; j < JJ; ++j) {
        f2v m; m.x = 0.f; m.y = 0.f;
        #pragma unroll
        for (int k = 0; k < JJ; ++k) {
          float a = adjs[j*JJ + k];
          m.x += a * h[k].x; m.y += a * h[k].y;
        }
        *(f2v*)&h1[(rb+j)*H1P + 2*lane] = m;
      }
    }
    __syncthreads();   // (2) mix complete

    // ---- combine (single phase): reads h1 (own slots), writes X planes
    //      (different buffers -> no intra-phase hazard)
    if (layer < NLAYERS - 1) {
      #pragma unroll
      for (int mt = 0; mt < 2; ++mt)
        #pragma unroll
        for (int q = 0; q < 16; ++q) {
          int row = wm*64 + mt*32 + (q&3) + 8*(q>>2) + 4*g;
          float x0v = (float)b2h((u16)(x0p[mt][q>>1] >> (16*(q&1))));
          float v = 0.2f*x0v + diag8[row]*acc0[mt][q] + h1[row*H1P + ccol] + biasl[ccol];
          _Float16 hh = (_Float16)v;
          xh[row*XP + ccol] = h2b(hh);
          xl[row*XP + ccol] = h2b((_Float16)(v - (float)hh));
        }
    } else {
      // final layer: keep f32, write h1 in place (own-slot RMW, race-free)
      #pragma unroll
      for (int mt = 0; mt < 2; ++mt)
        #pragma unroll
        for (int q = 0; q < 16; ++q) {
          int row = wm*64 + mt*32 + (q&3) + 8*(q>>2) + 4*g;
          float x0v = (float)b2h((u16)(x0p[mt][q>>1] >> (16*(q&1))));
          h1[row*H1P + ccol] = 0.2f*x0v + diag8[row]*acc0[mt][q] + h1[row*H1P + ccol] + biasl[ccol];
        }
    }
    __syncthreads();   // (3) ready for next layer / LN
  }

  // ---- LayerNorm + store (reads f32 h1)
  float ga = gamma[lane], g2 = gamma[64+lane];
  float ba = beta[lane],  b2f = beta[64+lane];
  #pragma unroll 1
  for (int i = 0; i < 16; ++i) {
    int r = wid + 8*i;             // wave-uniform
    if (r >= ROWS) continue;
    int grow = grow0 + r;
    if (grow >= totRows) continue;
    float xa = h1[r*H1P + lane];
    float xc = h1[r*H1P + 64 + lane];
    float mu = wred(xa + xc) * (1.f/128.f);
    float da = xa - mu, dc = xc - mu;
    float vs = wred(da*da + dc*dc) * (1.f/128.f);
    float rs = rsqrtf(vs + 1e-10f);
    size_t ob = (size_t)grow*CC;
    out[ob + lane]      = da*rs*ga + ba;
    out[ob + 64 + lane] = dc*rs*g2 + b2f;
  }
}

extern "C" void kernel_launch(void* const* d_in, const int* in_sizes, int n_in,
                              void* d_out, int out_size, void* d_ws, size_t ws_size,
                              hipStream_t stream) {
  const float* x   = (const float*)d_in[0];
  const float* x0  = (const float*)d_in[1];
  const float* adj = (const float*)d_in[2];
  const float* W0  = (const float*)d_in[3];
  const float* W1  = (const float*)d_in[4];
  const float* bv  = (const float*)d_in[5];
  const float* ga  = (const float*)d_in[6];
  const float* be  = (const float*)d_in[7];
  u16* wsH = (u16*)d_ws;                    // [2][128][128] f16
  int totRows = in_sizes[0] / CC;
  int nBatch  = totRows / JJ;
  int grid    = (nBatch + BB - 1) / BB;
  wprep<<<dim3(2), dim3(256), 0, stream>>>(W0, W1, wsH);
  hipFuncSetAttribute((const void*)gconv_fused,
                      hipFuncAttributeMaxDynamicSharedMemorySize, LDS_BYTES);
  gconv_fused<<<dim3(grid), dim3(NT), LDS_BYTES, stream>>>(
      x, x0, adj, wsH, bv, ga, be, (float*)d_out, totRows);
}